// Round 4
// baseline (884.173 us; speedup 1.0000x reference)
//
#include <hip/hip_runtime.h>

#define TLEN  512
#define HID   128
#define RSLOT 16   // ring slots/slice (L2-resident live set)

typedef __attribute__((ext_vector_type(8))) short          bf16x8;
typedef __attribute__((ext_vector_type(4))) float          f32x4;
typedef __attribute__((ext_vector_type(2))) float          f32x2;
typedef __attribute__((ext_vector_type(4))) unsigned short u16x4;
typedef unsigned long long u64;

#define LOG2E  1.4426950408889634f
#define LOG2E2 2.8853900817779268f

template<bool B> struct BC { static constexpr bool value = B; };
template<int I>  struct IC { static constexpr int  value = I; };

// RNE (cold paths)
__device__ __forceinline__ unsigned short f2bf(float f) {
    union { float f; unsigned u; } v; v.f = f;
    unsigned r = v.u + 0x7fffu + ((v.u >> 16) & 1u);
    return (unsigned short)(r >> 16);
}
// round-half-up (hot path: h)
__device__ __forceinline__ unsigned short f2bf_fast(float f) {
    union { float f; unsigned u; } v; v.f = f;
    return (unsigned short)((v.u + 0x8000u) >> 16);
}

// packed-lane helpers: exp2/rcp have no packed form -> per-element scalars;
// surrounding arithmetic stays f32x2 so the backend emits v_pk_{fma,mul,add}_f32.
__device__ __forceinline__ f32x2 exp2_2(f32x2 a) {
    f32x2 r; r.x = __builtin_exp2f(a.x); r.y = __builtin_exp2f(a.y); return r;
}
__device__ __forceinline__ f32x2 rcp_2(f32x2 a) {
    f32x2 r; r.x = __builtin_amdgcn_rcpf(a.x); r.y = __builtin_amdgcn_rcpf(a.y); return r;
}

// LDS granule swizzle: phi(g) = g ^ ((g>>4)&3) on 16B granules (R1: bank
// conflicts 7.9M -> 33K). Applied to every hbuf/xbuf access. Key algebra:
// phi is an involution and phi(kt*64+lane) = kt*64+(lane^quad), so ring
// words 2*(kt*64+lane),+1 ARE the A-fragment bytes for (lane,kt) — the
// consumer can load fragments straight from the ring (no LDS staging).

// Loads AGENT scope (L1-bypass -> same-XCD L2); stores WORKGROUP scope.
__device__ __forceinline__ int flag_peek(const int* f) {
    return __hip_atomic_load(f, __ATOMIC_RELAXED, __HIP_MEMORY_SCOPE_AGENT);
}
__device__ __forceinline__ int flag_spin(const int* f, int v) {
    int x = flag_peek(f);
    while (x < v) { __builtin_amdgcn_s_sleep(1); x = flag_peek(f); }
    return x;
}
__device__ __forceinline__ void flag_pub(int* f, int v) {
    __hip_atomic_store(f, v, __ATOMIC_RELAXED, __HIP_MEMORY_SCOPE_WORKGROUP);
}

// Split-GEMM LSTM layer: gates(t) = xacc(t) + h(t-1)@W_hh.
// Consumer layers (CONS) prefetch x A-fragments DIRECTLY from the L2 ring
// into registers 3 steps ahead (xfr[3][4], 8 u64 AGENT loads/step) — no
// xbuf LDS staging, halving LDS-pipe pressure per CU-step.
// Activation math is rcp-merged (5 exp2 + 3 rcp per cell) in f32x2 pairs.
template<int MODE, bool CONS, bool PROD, bool WFC>
__device__ __forceinline__ void run_layer_p(
    const float* __restrict__ xin,
    const u64* __restrict__ rin, u64* __restrict__ rout,
    const int* pin_flag, int* cout_flag, const int* cin_flag, int* pout_flag,
    const float* __restrict__ wih, const float* __restrict__ whh,
    const float* __restrict__ bih, const float* __restrict__ bhh,
    unsigned short (* __restrict__ hbuf)[2048],
    unsigned short (* __restrict__ xbuf)[2048],
    float* __restrict__ fcred,
    const int tid, const int wave, const int lane,
    const int n16, const int quad, const int bbase)
{
    constexpr int NKTX = MODE ? 4 : 1;    // x K-tiles of 32
    constexpr int DINL = MODE ? 128 : 6;  // real input features

    // ---- weights -> register B fragments (prescaled) ----
    bf16x8 Wfx[4][NKTX], Wfh[4][4];
    f32x4  bbv[4];
#pragma unroll
    for (int g = 0; g < 4; ++g) {
        const float sc = (g == 2) ? LOG2E2 : LOG2E;
        const int row = g * 128 + wave * 16 + n16;
        const float bg = (bih[row] + bhh[row]) * sc;
        f32x4 bi = {bg, bg, bg, bg};
        bbv[g] = bi;
#pragma unroll
        for (int kt = 0; kt < NKTX; ++kt) {
            bf16x8 wv;
#pragma unroll
            for (int j = 0; j < 8; ++j) {
                const int k = kt * 32 + quad * 8 + j;
                wv[j] = (short)f2bf(((k < DINL) ? wih[row * DINL + k] : 0.0f) * sc);
            }
            Wfx[g][kt] = wv;
        }
#pragma unroll
        for (int kt = 0; kt < 4; ++kt) {
            bf16x8 wv;
#pragma unroll
            for (int j = 0; j < 8; ++j) {
                const int k = kt * 32 + quad * 8 + j;
                wv[j] = (short)f2bf(whh[row * HID + k] * sc);
            }
            Wfh[g][kt] = wv;
        }
    }

    // ---- swizzled LDS offsets (loop-invariant) ----
    const int rof  = (lane ^ quad) * 8;                    // A-frag read: +kt*512
    const int j    = wave * 16 + n16;
    const int beta = ((j & 31) >> 3) & 3;
    const int wbase = ((j >> 5) * 64 + ((j & 31) >> 3) * 16 + quad * 4) * 8 + (j & 7);
    int wof[4];
#pragma unroll
    for (int r = 0; r < 4; ++r) wof[r] = wbase + ((r ^ beta) * 8);
    const int uof  = ((((tid >> 1) ^ ((tid >> 5) & 3))) << 3) + (tid & 1) * 4;
    const int xm = tid >> 5, xk = tid & 31;                // MODE0 commit map
    const int eiS = ((xk >> 3) * 16 + (xm ^ (xk >> 3))) * 8 + (xk & 7);

    // CONS: direct ring->register A-fragment load for entry e.
    // ring words 2*(kt*64+lane), +1 of entry e are exactly the 16 bytes
    // ds_read_b128 delivered for (lane,kt) under the phi swizzle.
    bf16x8 xfr[3][4];
    auto ring_frags = [&](int e, bf16x8 (&dst)[4]) {
        const u64* pb = rin + (size_t)((e & (RSLOT - 1)) * 512 + 2 * lane);
#pragma unroll
        for (int kt = 0; kt < 4; ++kt) {
            union { u64 d[2]; bf16x8 v; } u;
            u.d[0] = __hip_atomic_load(pb + kt * 128,
                                       __ATOMIC_RELAXED, __HIP_MEMORY_SCOPE_AGENT);
            u.d[1] = __hip_atomic_load(pb + kt * 128 + 1,
                                       __ATOMIC_RELAXED, __HIP_MEMORY_SCOPE_AGENT);
            dst[kt] = u.v;
        }
    };

    // ---- prologue ----
    { u16x4 z = {0, 0, 0, 0}; *(u16x4*)&hbuf[0][uof] = z; }   // h(-1)=0
    float pfx0 = 0.0f;
    int pend = 0, cpend = 0;
    if constexpr (CONS) {
        // entries 0..2 -> xfr[0..2] (entry e readable when flag >= e+1)
        flag_spin(pin_flag, 1); ring_frags(0, xfr[0]);
        flag_spin(pin_flag, 2); ring_frags(1, xfr[1]);
        pend = flag_spin(pin_flag, 3); ring_frags(2, xfr[2]);
    } else {
        // commit x(0),x(1); prefetch x(2)
        float v0 = (xk < DINL) ? xin[((bbase + xm) * TLEN + 0) * DINL + xk] : 0.0f;
        float v1 = (xk < DINL) ? xin[((bbase + xm) * TLEN + 1) * DINL + xk] : 0.0f;
        xbuf[0][eiS] = f2bf(v0);
        xbuf[1][eiS] = f2bf(v1);
        if (xk < DINL) pfx0 = xin[((bbase + xm) * TLEN + 2) * DINL + xk];
    }
    if constexpr (PROD) cpend = -(1 << 30);
    __syncthreads();   // xbuf[0..1] (MODE0), hbuf[0] visible

    // xacc(0) = bias + x(0)@Wx  (bias enters as the C-operand of kt=0)
    f32x4 accA[4], accB[4];
#pragma unroll
    for (int kt = 0; kt < NKTX; ++kt) {
        bf16x8 a;
        if constexpr (CONS) a = xfr[0][kt];
        else                a = *(const bf16x8*)&xbuf[0][rof + kt * 512];
#pragma unroll
        for (int g = 0; g < 4; ++g)
            accA[g] = __builtin_amdgcn_mfma_f32_16x16x32_bf16(
                a, Wfx[g][kt], (kt == 0) ? bbv[g] : accA[g], 0, 0, 0);
    }

    f32x2 cst2[2] = {{0.f, 0.f}, {0.f, 0.f}};
    float hf[4];

    // SH: compute shadow xacc(t+1). CM: commit x(t+2) (MODE0 only).
    // CUR/RD/WR compile-time; CONS frag slots: consume RD=(t+1)%3,
    // load LD=(RD+2)%3=t%3 with entry t+3.
    auto step = [&](auto SHc, auto CMc, auto CURc, auto RDc, auto WRc,
                    f32x4 (&accC)[4], f32x4 (&accN)[4], int t) {
        constexpr bool SH  = decltype(SHc)::value;
        constexpr bool CM  = decltype(CMc)::value;
        constexpr int  CUR = decltype(CURc)::value;
        constexpr int  NXT = CUR ^ 1;
        constexpr int  RD  = decltype(RDc)::value;
        constexpr int  WR  = decltype(WRc)::value;
        constexpr int  LD  = (RD + 2) % 3;
        __syncthreads();   // hbuf[CUR], xbuf[RD] ready; all vmem drained

        const unsigned short* __restrict__ hcur = hbuf[CUR];
        const unsigned short* __restrict__ xrd  = xbuf[RD];

        // ---- critical A-frag loads issue first after the barrier ----
        bf16x8 ha_[4], xa_[NKTX];
#pragma unroll
        for (int kt = 0; kt < 4; ++kt) ha_[kt] = *(const bf16x8*)&hcur[rof + kt * 512];
        if constexpr (SH && !CONS) {
#pragma unroll
            for (int kt = 0; kt < NKTX; ++kt)
                xa_[kt] = *(const bf16x8*)&xrd[rof + kt * 512];
        }

        // ---- shadow: ring->register fragment prefetch of entry t+3 ----
        if constexpr (CONS) {
            if (t + 3 < TLEN) {
                if (pend < t + 4) pend = flag_spin(pin_flag, t + 4);   // rare
                ring_frags(t + 3, xfr[LD]);
                pend = flag_peek(pin_flag);
            }
        }
        // ---- publish progress (cout = t+4: read through entry t+3) ----
        if (tid == 0) {
            if constexpr (CONS) if ((t & 3) == 0) flag_pub(cout_flag, t + 4);
            if constexpr (PROD) if (t >= 2)       flag_pub(pout_flag, t - 1);
        }
        // ---- producer: store entry t-1 (h(t-1) in hbuf[CUR]) ----
        if constexpr (PROD) {
            if (t >= 1) {
                const int e = t - 1;
                if ((e & 3) == 0 && e + 4 > RSLOT && cpend < e + 4 - RSLOT)
                    cpend = flag_spin(cin_flag, e + 4 - RSLOT);        // rare
                u64 hv = *(const u64*)&hcur[uof];
                __hip_atomic_store(rout + (e & (RSLOT - 1)) * 512 + tid, hv,
                                   __ATOMIC_RELAXED, __HIP_MEMORY_SCOPE_WORKGROUP);
                if ((e & 3) == 1) cpend = flag_peek(cin_flag);
            }
        }
        // ---- shadow: global x prefetch (MODE0) ----
        float pfx1 = 0.0f;
        if constexpr (!CONS) {
            if (t + 3 < TLEN && xk < DINL)
                pfx1 = xin[((bbase + xm) * TLEN + (t + 3)) * DINL + xk];
        }

        // ---- CRITICAL: gates = xacc(t) + h(t-1)@W_hh ----
#pragma unroll
        for (int kt = 0; kt < 4; ++kt)
#pragma unroll
            for (int g = 0; g < 4; ++g)
                accC[g] = __builtin_amdgcn_mfma_f32_16x16x32_bf16(ha_[kt], Wfh[g][kt], accC[g], 0, 0, 0);

        // ---- SHADOW: xacc(t+1) = bias + x(t+1)@W_ih ----
        if constexpr (SH) {
#pragma unroll
            for (int kt = 0; kt < NKTX; ++kt) {
                bf16x8 a;
                if constexpr (CONS) a = xfr[RD][kt];
                else                a = xa_[kt];
#pragma unroll
                for (int g = 0; g < 4; ++g)
                    accN[g] = __builtin_amdgcn_mfma_f32_16x16x32_bf16(
                        a, Wfx[g][kt], (kt == 0) ? bbv[g] : accN[g], 0, 0, 0);
            }
        }

        // ---- cell update: rcp-merged, packed f32 over r-pairs ----
        const f32x2 one = {1.0f, 1.0f};
#pragma unroll
        for (int p = 0; p < 2; ++p) {
            const f32x2 gi = {accC[0][2 * p], accC[0][2 * p + 1]};
            const f32x2 gf = {accC[1][2 * p], accC[1][2 * p + 1]};
            const f32x2 gg = {accC[2][2 * p], accC[2][2 * p + 1]};
            const f32x2 go = {accC[3][2 * p], accC[3][2 * p + 1]};
            const f32x2 A  = exp2_2(-gi);
            const f32x2 Fv = rcp_2(one + exp2_2(-gf));
            const f32x2 E  = exp2_2(-gg);
            const f32x2 D  = exp2_2(-go);
            const f32x2 ig = (one - E) * rcp_2((one + A) * (one + E));
            const f32x2 c  = Fv * cst2[p] + ig;
            cst2[p] = c;
            f32x2 y = c * (f32x2){LOG2E2, LOG2E2};
            y.x = fminf(fmaxf(y.x, -30.0f), 30.0f);
            y.y = fminf(fmaxf(y.y, -30.0f), 30.0f);
            const f32x2 Cn = exp2_2(-y);
            const f32x2 h2 = (one - Cn) * rcp_2((one + D) * (one + Cn));
            if constexpr (WFC) { hf[2 * p] = h2.x; hf[2 * p + 1] = h2.y; }
            hbuf[NXT][wof[2 * p]]     = f2bf_fast(h2.x);
            hbuf[NXT][wof[2 * p + 1]] = f2bf_fast(h2.y);
        }
        if constexpr (WFC) {
            if (t == TLEN - 1)
#pragma unroll
                for (int r = 0; r < 4; ++r)
                    fcred[(quad * 4 + r) * HID + wave * 16 + n16] = hf[r];
        }
        // ---- commit x(t+2) -> xbuf[WR] (MODE0 only) ----
        if constexpr (CM && !CONS) {
            xbuf[WR][eiS] = f2bf(pfx0);
            pfx0 = pfx1;
        }
    };

    // rd(t)=(t+1)%3, wr(t)=(t+2)%3; 510 = 6*85 -> all constants per instance
    for (int t = 0; t < TLEN - 2; t += 6) {
        step(BC<true>{}, BC<true>{}, IC<0>{}, IC<1>{}, IC<2>{}, accA, accB, t);
        step(BC<true>{}, BC<true>{}, IC<1>{}, IC<2>{}, IC<0>{}, accB, accA, t + 1);
        step(BC<true>{}, BC<true>{}, IC<0>{}, IC<0>{}, IC<1>{}, accA, accB, t + 2);
        step(BC<true>{}, BC<true>{}, IC<1>{}, IC<1>{}, IC<2>{}, accB, accA, t + 3);
        step(BC<true>{}, BC<true>{}, IC<0>{}, IC<2>{}, IC<0>{}, accA, accB, t + 4);
        step(BC<true>{}, BC<true>{}, IC<1>{}, IC<0>{}, IC<1>{}, accB, accA, t + 5);
    }
    step(BC<true>{},  BC<false>{}, IC<0>{}, IC<1>{}, IC<2>{}, accA, accB, TLEN - 2);
    step(BC<false>{}, BC<false>{}, IC<1>{}, IC<2>{}, IC<0>{}, accB, accA, TLEN - 1);

    // ---- producer epilogue: flush entry T-1 ----
    if constexpr (PROD) {
        __syncthreads();   // h(T-1) in hbuf[0]; step T-1 stores drained
        if (tid == 0) flag_pub(pout_flag, TLEN - 1);
        {
            flag_spin(cin_flag, TLEN - RSLOT);
            u64 hv = *(const u64*)&hbuf[TLEN & 1][uof];
            __hip_atomic_store(rout + ((TLEN - 1) & (RSLOT - 1)) * 512 + tid, hv,
                               __ATOMIC_RELAXED, __HIP_MEMORY_SCOPE_WORKGROUP);
        }
        __syncthreads();
        if (tid == 0) flag_pub(pout_flag, TLEN);
    }
}

extern "C" __global__ __launch_bounds__(512, 1)
void lstm3_pipe_kernel(const float* __restrict__ xin,
    const float* __restrict__ wih0, const float* __restrict__ whh0,
    const float* __restrict__ bih0, const float* __restrict__ bhh0,
    const float* __restrict__ wih1, const float* __restrict__ whh1,
    const float* __restrict__ bih1, const float* __restrict__ bhh1,
    const float* __restrict__ wih2, const float* __restrict__ whh2,
    const float* __restrict__ bih2, const float* __restrict__ bhh2,
    const float* __restrict__ fcw, const float* __restrict__ fcb,
    float* __restrict__ out,
    int* __restrict__ flags, u64* __restrict__ ring0, u64* __restrict__ ring1)
{
    __shared__ unsigned short hbuf[2][2048];   // 8 KB
    __shared__ unsigned short xbuf[3][2048];   // 12 KB (MODE0 uses 512/slot)
    __shared__ float fcred[16 * HID];          // 8 KB

    const int tid   = threadIdx.x;
    const int wave  = tid >> 6;
    const int lane  = tid & 63;
    const int n16   = lane & 15;
    const int quad  = lane >> 4;

    // bid = ((s>>3)*3 + layer)*8 + (s&7): all 3 stages of slice s on one XCD
    const int xcd    = blockIdx.x & 7;
    const int grp    = blockIdx.x >> 3;
    const int layer  = grp % 3;
    const int sgroup = grp / 3;
    const int slice  = sgroup * 8 + xcd;
    const int bbase  = slice * 16;

    u64* r0 = ring0 + (size_t)slice * (RSLOT * 512);
    u64* r1 = ring1 + (size_t)slice * (RSLOT * 512);
    int* prod0 = flags + (size_t)(0 * 64 + slice) * 64;
    int* prod1 = flags + (size_t)(1 * 64 + slice) * 64;
    int* cons1 = flags + (size_t)(2 * 64 + slice) * 64;
    int* cons2 = flags + (size_t)(3 * 64 + slice) * 64;

    if (layer == 0) {
        run_layer_p<0, false, true, false>(xin, nullptr, r0,
            nullptr, nullptr, cons1, prod0,
            wih0, whh0, bih0, bhh0, hbuf, xbuf, fcred, tid, wave, lane, n16, quad, bbase);
    } else if (layer == 1) {
        run_layer_p<1, true, true, false>(nullptr, r0, r1,
            prod0, cons1, cons2, prod1,
            wih1, whh1, bih1, bhh1, hbuf, xbuf, fcred, tid, wave, lane, n16, quad, bbase);
    } else {
        run_layer_p<1, true, false, true>(nullptr, r1, nullptr,
            prod1, cons2, nullptr, nullptr,
            wih2, whh2, bih2, bhh2, hbuf, xbuf, fcred, tid, wave, lane, n16, quad, bbase);
        __syncthreads();
        if (tid < 16) {
            float s = 0.0f;
#pragma unroll 8
            for (int j = 0; j < HID; ++j) s += fcw[j] * fcred[tid * HID + j];
            out[bbase + tid] = s + fcb[0];
        }
    }
}

extern "C" void kernel_launch(void* const* d_in, const int* in_sizes, int n_in,
                              void* d_out, int out_size, void* d_ws, size_t ws_size,
                              hipStream_t stream) {
    (void)in_sizes; (void)n_in; (void)out_size; (void)ws_size;
    const float* x    = (const float*)d_in[0];
    const float* wih0 = (const float*)d_in[1];
    const float* whh0 = (const float*)d_in[2];
    const float* bih0 = (const float*)d_in[3];
    const float* bhh0 = (const float*)d_in[4];
    const float* wih1 = (const float*)d_in[5];
    const float* whh1 = (const float*)d_in[6];
    const float* bih1 = (const float*)d_in[7];
    const float* bhh1 = (const float*)d_in[8];
    const float* wih2 = (const float*)d_in[9];
    const float* whh2 = (const float*)d_in[10];
    const float* bih2 = (const float*)d_in[11];
    const float* bhh2 = (const float*)d_in[12];
    const float* fcw  = (const float*)d_in[13];
    const float* fcb  = (const float*)d_in[14];
    float* out = (float*)d_out;

    // ws: flags 64 KB (poison-negative = not ready), ring0 4 MB, ring1 4 MB
    int* flags = (int*)d_ws;
    u64* ring0 = (u64*)((char*)d_ws + 65536);
    u64* ring1 = ring0 + (size_t)64 * RSLOT * 512;

    lstm3_pipe_kernel<<<dim3(192), dim3(512), 0, stream>>>(
        x, wih0, whh0, bih0, bhh0, wih1, whh1, bih1, bhh1,
        wih2, whh2, bih2, bhh2, fcw, fcb, out, flags, ring0, ring1);
}

// Round 5
// 761.833 us; speedup vs baseline: 1.1606x; 1.1606x over previous
//
#include <hip/hip_runtime.h>

#define TLEN  512
#define HID   128
#define RSLOT 16   // ring slots/slice (L2-resident live set)

typedef __attribute__((ext_vector_type(8))) short          bf16x8;
typedef __attribute__((ext_vector_type(4))) float          f32x4;
typedef __attribute__((ext_vector_type(2))) float          f32x2;
typedef __attribute__((ext_vector_type(4))) unsigned short u16x4;
typedef unsigned long long u64;

#define LOG2E  1.4426950408889634f
#define LOG2E2 2.8853900817779268f

template<bool B> struct BC { static constexpr bool value = B; };
template<int I>  struct IC { static constexpr int  value = I; };

// RNE (cold paths)
__device__ __forceinline__ unsigned short f2bf(float f) {
    union { float f; unsigned u; } v; v.f = f;
    unsigned r = v.u + 0x7fffu + ((v.u >> 16) & 1u);
    return (unsigned short)(r >> 16);
}
// round-half-up (hot path: h)
__device__ __forceinline__ unsigned short f2bf_fast(float f) {
    union { float f; unsigned u; } v; v.f = f;
    return (unsigned short)((v.u + 0x8000u) >> 16);
}

// packed-lane helpers: exp2/rcp have no packed form -> per-element scalars;
// surrounding arithmetic stays f32x2 so the backend emits v_pk_{fma,mul,add}_f32.
__device__ __forceinline__ f32x2 exp2_2(f32x2 a) {
    f32x2 r; r.x = __builtin_exp2f(a.x); r.y = __builtin_exp2f(a.y); return r;
}
__device__ __forceinline__ f32x2 rcp_2(f32x2 a) {
    f32x2 r; r.x = __builtin_amdgcn_rcpf(a.x); r.y = __builtin_amdgcn_rcpf(a.y); return r;
}

// LDS granule swizzle: phi(g) = g ^ ((g>>4)&3) on 16B granules (R1: bank
// conflicts 7.9M -> 33K). Applied to every hbuf/xbuf access.
// R4 lesson: x-path must stay in LDS — direct ring->register loads expose
// L2 latency at the per-step vmcnt(0) barrier drain (+360 cyc/step).

// Loads AGENT scope (L1-bypass -> same-XCD L2); stores WORKGROUP scope.
__device__ __forceinline__ int flag_peek(const int* f) {
    return __hip_atomic_load(f, __ATOMIC_RELAXED, __HIP_MEMORY_SCOPE_AGENT);
}
__device__ __forceinline__ int flag_spin(const int* f, int v) {
    int x = flag_peek(f);
    while (x < v) { __builtin_amdgcn_s_sleep(1); x = flag_peek(f); }
    return x;
}
__device__ __forceinline__ void flag_pub(int* f, int v) {
    __hip_atomic_store(f, v, __ATOMIC_RELAXED, __HIP_MEMORY_SCOPE_WORKGROUP);
}

// Split-GEMM LSTM layer: gates(t) = xacc(t) + h(t-1)@W_hh.
// LDS-burst discipline: only the CRITICAL ha_ reads issue in the post-barrier
// burst (32 b128/CU); the shadow xa_ reads are pinned (sched_barrier) below
// the critical MFMA so they drain under MFMA issue instead of queueing ahead
// of other waves' ha_ reads on the shared LDS pipe.
template<int MODE, bool CONS, bool PROD, bool WFC>
__device__ __forceinline__ void run_layer_p(
    const float* __restrict__ xin,
    const u64* __restrict__ rin, u64* __restrict__ rout,
    const int* pin_flag, int* cout_flag, const int* cin_flag, int* pout_flag,
    const float* __restrict__ wih, const float* __restrict__ whh,
    const float* __restrict__ bih, const float* __restrict__ bhh,
    unsigned short (* __restrict__ hbuf)[2048],
    unsigned short (* __restrict__ xbuf)[2048],
    float* __restrict__ fcred,
    const int tid, const int wave, const int lane,
    const int n16, const int quad, const int bbase)
{
    constexpr int NKTX = MODE ? 4 : 1;    // x K-tiles of 32
    constexpr int DINL = MODE ? 128 : 6;  // real input features

    // ---- weights -> register B fragments (prescaled) ----
    bf16x8 Wfx[4][NKTX], Wfh[4][4];
    f32x4  bbv[4];
#pragma unroll
    for (int g = 0; g < 4; ++g) {
        const float sc = (g == 2) ? LOG2E2 : LOG2E;
        const int row = g * 128 + wave * 16 + n16;
        const float bg = (bih[row] + bhh[row]) * sc;
        f32x4 bi = {bg, bg, bg, bg};
        bbv[g] = bi;
#pragma unroll
        for (int kt = 0; kt < NKTX; ++kt) {
            bf16x8 wv;
#pragma unroll
            for (int j = 0; j < 8; ++j) {
                const int k = kt * 32 + quad * 8 + j;
                wv[j] = (short)f2bf(((k < DINL) ? wih[row * DINL + k] : 0.0f) * sc);
            }
            Wfx[g][kt] = wv;
        }
#pragma unroll
        for (int kt = 0; kt < 4; ++kt) {
            bf16x8 wv;
#pragma unroll
            for (int j = 0; j < 8; ++j) {
                const int k = kt * 32 + quad * 8 + j;
                wv[j] = (short)f2bf(whh[row * HID + k] * sc);
            }
            Wfh[g][kt] = wv;
        }
    }

    // ---- swizzled LDS offsets (loop-invariant) ----
    const int rof  = (lane ^ quad) * 8;                    // A-frag read: +kt*512
    const int j    = wave * 16 + n16;
    const int beta = ((j & 31) >> 3) & 3;
    const int wbase = ((j >> 5) * 64 + ((j & 31) >> 3) * 16 + quad * 4) * 8 + (j & 7);
    int wof[4];
#pragma unroll
    for (int r = 0; r < 4; ++r) wof[r] = wbase + ((r ^ beta) * 8);
    const int uof  = ((((tid >> 1) ^ ((tid >> 5) & 3))) << 3) + (tid & 1) * 4;
    const int xm = tid >> 5, xk = tid & 31;                // MODE0 commit map
    const int eiS = ((xk >> 3) * 16 + (xm ^ (xk >> 3))) * 8 + (xk & 7);

    // ---- prologue ----
    { u16x4 z = {0, 0, 0, 0}; *(u16x4*)&hbuf[0][uof] = z; }   // h(-1)=0
    u64 q0 = 0, q1 = 0, q2 = 0, qn = 0;
    float pfx0 = 0.0f;
    int pend = 0, cpend = 0;
    if constexpr (CONS) {
        // commit entries 0,1 -> xbuf[0],xbuf[1]; queue entries 2..4
        flag_spin(pin_flag, 1);
        *(u64*)&xbuf[0][uof] =
            __hip_atomic_load(rin + tid, __ATOMIC_RELAXED, __HIP_MEMORY_SCOPE_AGENT);
        flag_spin(pin_flag, 2);
        *(u64*)&xbuf[1][uof] =
            __hip_atomic_load(rin + 512 + tid, __ATOMIC_RELAXED, __HIP_MEMORY_SCOPE_AGENT);
        pend = flag_spin(pin_flag, 5);
        q0 = __hip_atomic_load(rin + 2 * 512 + tid, __ATOMIC_RELAXED, __HIP_MEMORY_SCOPE_AGENT);
        q1 = __hip_atomic_load(rin + 3 * 512 + tid, __ATOMIC_RELAXED, __HIP_MEMORY_SCOPE_AGENT);
        q2 = __hip_atomic_load(rin + 4 * 512 + tid, __ATOMIC_RELAXED, __HIP_MEMORY_SCOPE_AGENT);
    } else {
        // commit x(0),x(1); prefetch x(2)
        float v0 = (xk < DINL) ? xin[((bbase + xm) * TLEN + 0) * DINL + xk] : 0.0f;
        float v1 = (xk < DINL) ? xin[((bbase + xm) * TLEN + 1) * DINL + xk] : 0.0f;
        xbuf[0][eiS] = f2bf(v0);
        xbuf[1][eiS] = f2bf(v1);
        if (xk < DINL) pfx0 = xin[((bbase + xm) * TLEN + 2) * DINL + xk];
    }
    if constexpr (PROD) cpend = -(1 << 30);
    __syncthreads();   // xbuf[0..1], hbuf[0] visible

    // xacc(0) = bias + x(0)@Wx  (bias enters as the C-operand of kt=0)
    f32x4 accA[4], accB[4];
#pragma unroll
    for (int kt = 0; kt < NKTX; ++kt) {
        bf16x8 a = *(const bf16x8*)&xbuf[0][rof + kt * 512];
#pragma unroll
        for (int g = 0; g < 4; ++g)
            accA[g] = __builtin_amdgcn_mfma_f32_16x16x32_bf16(
                a, Wfx[g][kt], (kt == 0) ? bbv[g] : accA[g], 0, 0, 0);
    }

    f32x2 cst2[2] = {{0.f, 0.f}, {0.f, 0.f}};
    float hf[4];

    // SH: compute shadow xacc(t+1). CM: commit x(t+2). CUR/RD/WR compile-time.
    auto step = [&](auto SHc, auto CMc, auto CURc, auto RDc, auto WRc,
                    f32x4 (&accC)[4], f32x4 (&accN)[4], int t) {
        constexpr bool SH  = decltype(SHc)::value;
        constexpr bool CM  = decltype(CMc)::value;
        constexpr int  CUR = decltype(CURc)::value;
        constexpr int  NXT = CUR ^ 1;
        constexpr int  RD  = decltype(RDc)::value;
        constexpr int  WR  = decltype(WRc)::value;
        __syncthreads();   // hbuf[CUR], xbuf[RD] ready; all vmem drained

        const unsigned short* __restrict__ hcur = hbuf[CUR];
        const unsigned short* __restrict__ xrd  = xbuf[RD];

        // ---- CRITICAL A-frag loads only: post-barrier LDS burst is 32
        //      b128/CU (was 64 with xa_ here) ----
        bf16x8 ha_[4];
#pragma unroll
        for (int kt = 0; kt < 4; ++kt) ha_[kt] = *(const bf16x8*)&hcur[rof + kt * 512];

        // ---- shadow: ring load entry t+5 ----
        if constexpr (CONS) {
            if (t + 5 < TLEN) {
                if (pend < t + 6) pend = flag_spin(pin_flag, t + 6);   // rare
                qn = __hip_atomic_load(rin + ((t + 5) & (RSLOT - 1)) * 512 + tid,
                                       __ATOMIC_RELAXED, __HIP_MEMORY_SCOPE_AGENT);
                pend = flag_peek(pin_flag);
            }
        }
        // ---- publish progress ----
        if (tid == 0) {
            if constexpr (CONS) if ((t & 3) == 0) flag_pub(cout_flag, t + 5);
            if constexpr (PROD) if (t >= 2)       flag_pub(pout_flag, t - 1);
        }
        // ---- producer: store entry t-1 (h(t-1) in hbuf[CUR]) ----
        if constexpr (PROD) {
            if (t >= 1) {
                const int e = t - 1;
                if ((e & 3) == 0 && e + 4 > RSLOT && cpend < e + 4 - RSLOT)
                    cpend = flag_spin(cin_flag, e + 4 - RSLOT);        // rare
                u64 hv = *(const u64*)&hcur[uof];
                __hip_atomic_store(rout + (e & (RSLOT - 1)) * 512 + tid, hv,
                                   __ATOMIC_RELAXED, __HIP_MEMORY_SCOPE_WORKGROUP);
                if ((e & 3) == 1) cpend = flag_peek(cin_flag);
            }
        }
        // ---- shadow: global x prefetch (MODE0) ----
        float pfx1 = 0.0f;
        if constexpr (!CONS) {
            if (t + 3 < TLEN && xk < DINL)
                pfx1 = xin[((bbase + xm) * TLEN + (t + 3)) * DINL + xk];
        }

        // ---- CRITICAL: gates = xacc(t) + h(t-1)@W_hh ----
#pragma unroll
        for (int kt = 0; kt < 4; ++kt)
#pragma unroll
            for (int g = 0; g < 4; ++g)
                accC[g] = __builtin_amdgcn_mfma_f32_16x16x32_bf16(ha_[kt], Wfh[g][kt], accC[g], 0, 0, 0);

        // ---- shadow xa_ reads pinned BELOW the critical MFMAs: they have a
        //      full step of slack and must not occupy the post-barrier LDS
        //      queue ahead of other waves' critical ha_ reads ----
        __builtin_amdgcn_sched_barrier(0);
        bf16x8 xa_[NKTX];
        if constexpr (SH) {
#pragma unroll
            for (int kt = 0; kt < NKTX; ++kt)
                xa_[kt] = *(const bf16x8*)&xrd[rof + kt * 512];
        }

        // ---- SHADOW: xacc(t+1) = bias + x(t+1)@W_ih ----
        if constexpr (SH) {
#pragma unroll
            for (int kt = 0; kt < NKTX; ++kt)
#pragma unroll
                for (int g = 0; g < 4; ++g)
                    accN[g] = __builtin_amdgcn_mfma_f32_16x16x32_bf16(
                        xa_[kt], Wfx[g][kt], (kt == 0) ? bbv[g] : accN[g], 0, 0, 0);
        }

        // ---- cell update: rcp-merged, packed f32 over r-pairs ----
        const f32x2 one = {1.0f, 1.0f};
#pragma unroll
        for (int p = 0; p < 2; ++p) {
            const f32x2 gi = {accC[0][2 * p], accC[0][2 * p + 1]};
            const f32x2 gf = {accC[1][2 * p], accC[1][2 * p + 1]};
            const f32x2 gg = {accC[2][2 * p], accC[2][2 * p + 1]};
            const f32x2 go = {accC[3][2 * p], accC[3][2 * p + 1]};
            const f32x2 A  = exp2_2(-gi);
            const f32x2 Fv = rcp_2(one + exp2_2(-gf));
            const f32x2 E  = exp2_2(-gg);
            const f32x2 D  = exp2_2(-go);
            const f32x2 ig = (one - E) * rcp_2((one + A) * (one + E));
            const f32x2 c  = Fv * cst2[p] + ig;
            cst2[p] = c;
            f32x2 y;
            y.x = __builtin_amdgcn_fmed3f(c.x * LOG2E2, -30.0f, 30.0f);
            y.y = __builtin_amdgcn_fmed3f(c.y * LOG2E2, -30.0f, 30.0f);
            const f32x2 Cn = exp2_2(-y);
            const f32x2 h2 = (one - Cn) * rcp_2((one + D) * (one + Cn));
            if constexpr (WFC) { hf[2 * p] = h2.x; hf[2 * p + 1] = h2.y; }
            hbuf[NXT][wof[2 * p]]     = f2bf_fast(h2.x);
            hbuf[NXT][wof[2 * p + 1]] = f2bf_fast(h2.y);
        }
        if constexpr (WFC) {
            if (t == TLEN - 1)
#pragma unroll
                for (int r = 0; r < 4; ++r)
                    fcred[(quad * 4 + r) * HID + wave * 16 + n16] = hf[r];
        }
        // ---- commit x(t+2) -> xbuf[WR]; shift queue ----
        if constexpr (CM) {
            if constexpr (CONS) {
                *(u64*)&xbuf[WR][uof] = q0;
                q0 = q1; q1 = q2; q2 = qn;
            } else {
                xbuf[WR][eiS] = f2bf(pfx0);
                pfx0 = pfx1;
            }
        }
    };

    // rd(t)=(t+1)%3, wr(t)=(t+2)%3; 510 = 6*85 -> all constants per instance
    for (int t = 0; t < TLEN - 2; t += 6) {
        step(BC<true>{}, BC<true>{}, IC<0>{}, IC<1>{}, IC<2>{}, accA, accB, t);
        step(BC<true>{}, BC<true>{}, IC<1>{}, IC<2>{}, IC<0>{}, accB, accA, t + 1);
        step(BC<true>{}, BC<true>{}, IC<0>{}, IC<0>{}, IC<1>{}, accA, accB, t + 2);
        step(BC<true>{}, BC<true>{}, IC<1>{}, IC<1>{}, IC<2>{}, accB, accA, t + 3);
        step(BC<true>{}, BC<true>{}, IC<0>{}, IC<2>{}, IC<0>{}, accA, accB, t + 4);
        step(BC<true>{}, BC<true>{}, IC<1>{}, IC<0>{}, IC<1>{}, accB, accA, t + 5);
    }
    step(BC<true>{},  BC<false>{}, IC<0>{}, IC<1>{}, IC<2>{}, accA, accB, TLEN - 2);
    step(BC<false>{}, BC<false>{}, IC<1>{}, IC<2>{}, IC<0>{}, accB, accA, TLEN - 1);

    // ---- producer epilogue: flush entry T-1 ----
    if constexpr (PROD) {
        __syncthreads();   // h(T-1) in hbuf[0]; step T-1 stores drained
        if (tid == 0) flag_pub(pout_flag, TLEN - 1);
        {
            flag_spin(cin_flag, TLEN - RSLOT);
            u64 hv = *(const u64*)&hbuf[TLEN & 1][uof];
            __hip_atomic_store(rout + ((TLEN - 1) & (RSLOT - 1)) * 512 + tid, hv,
                               __ATOMIC_RELAXED, __HIP_MEMORY_SCOPE_WORKGROUP);
        }
        __syncthreads();
        if (tid == 0) flag_pub(pout_flag, TLEN);
    }
}

extern "C" __global__ __launch_bounds__(512, 1)
void lstm3_pipe_kernel(const float* __restrict__ xin,
    const float* __restrict__ wih0, const float* __restrict__ whh0,
    const float* __restrict__ bih0, const float* __restrict__ bhh0,
    const float* __restrict__ wih1, const float* __restrict__ whh1,
    const float* __restrict__ bih1, const float* __restrict__ bhh1,
    const float* __restrict__ wih2, const float* __restrict__ whh2,
    const float* __restrict__ bih2, const float* __restrict__ bhh2,
    const float* __restrict__ fcw, const float* __restrict__ fcb,
    float* __restrict__ out,
    int* __restrict__ flags, u64* __restrict__ ring0, u64* __restrict__ ring1)
{
    __shared__ unsigned short hbuf[2][2048];   // 8 KB
    __shared__ unsigned short xbuf[3][2048];   // 12 KB (MODE0 uses 512/slot)
    __shared__ float fcred[16 * HID];          // 8 KB

    const int tid   = threadIdx.x;
    const int wave  = tid >> 6;
    const int lane  = tid & 63;
    const int n16   = lane & 15;
    const int quad  = lane >> 4;

    // bid = ((s>>3)*3 + layer)*8 + (s&7): all 3 stages of slice s on one XCD
    const int xcd    = blockIdx.x & 7;
    const int grp    = blockIdx.x >> 3;
    const int layer  = grp % 3;
    const int sgroup = grp / 3;
    const int slice  = sgroup * 8 + xcd;
    const int bbase  = slice * 16;

    u64* r0 = ring0 + (size_t)slice * (RSLOT * 512);
    u64* r1 = ring1 + (size_t)slice * (RSLOT * 512);
    int* prod0 = flags + (size_t)(0 * 64 + slice) * 64;
    int* prod1 = flags + (size_t)(1 * 64 + slice) * 64;
    int* cons1 = flags + (size_t)(2 * 64 + slice) * 64;
    int* cons2 = flags + (size_t)(3 * 64 + slice) * 64;

    if (layer == 0) {
        run_layer_p<0, false, true, false>(xin, nullptr, r0,
            nullptr, nullptr, cons1, prod0,
            wih0, whh0, bih0, bhh0, hbuf, xbuf, fcred, tid, wave, lane, n16, quad, bbase);
    } else if (layer == 1) {
        run_layer_p<1, true, true, false>(nullptr, r0, r1,
            prod0, cons1, cons2, prod1,
            wih1, whh1, bih1, bhh1, hbuf, xbuf, fcred, tid, wave, lane, n16, quad, bbase);
    } else {
        run_layer_p<1, true, false, true>(nullptr, r1, nullptr,
            prod1, cons2, nullptr, nullptr,
            wih2, whh2, bih2, bhh2, hbuf, xbuf, fcred, tid, wave, lane, n16, quad, bbase);
        __syncthreads();
        if (tid < 16) {
            float s = 0.0f;
#pragma unroll 8
            for (int j = 0; j < HID; ++j) s += fcw[j] * fcred[tid * HID + j];
            out[bbase + tid] = s + fcb[0];
        }
    }
}

extern "C" void kernel_launch(void* const* d_in, const int* in_sizes, int n_in,
                              void* d_out, int out_size, void* d_ws, size_t ws_size,
                              hipStream_t stream) {
    (void)in_sizes; (void)n_in; (void)out_size; (void)ws_size;
    const float* x    = (const float*)d_in[0];
    const float* wih0 = (const float*)d_in[1];
    const float* whh0 = (const float*)d_in[2];
    const float* bih0 = (const float*)d_in[3];
    const float* bhh0 = (const float*)d_in[4];
    const float* wih1 = (const float*)d_in[5];
    const float* whh1 = (const float*)d_in[6];
    const float* bih1 = (const float*)d_in[7];
    const float* bhh1 = (const float*)d_in[8];
    const float* wih2 = (const float*)d_in[9];
    const float* whh2 = (const float*)d_in[10];
    const float* bih2 = (const float*)d_in[11];
    const float* bhh2 = (const float*)d_in[12];
    const float* fcw  = (const float*)d_in[13];
    const float* fcb  = (const float*)d_in[14];
    float* out = (float*)d_out;

    // ws: flags 64 KB (poison-negative = not ready), ring0 4 MB, ring1 4 MB
    int* flags = (int*)d_ws;
    u64* ring0 = (u64*)((char*)d_ws + 65536);
    u64* ring1 = ring0 + (size_t)64 * RSLOT * 512;

    lstm3_pipe_kernel<<<dim3(192), dim3(512), 0, stream>>>(
        x, wih0, whh0, bih0, bhh0, wih1, whh1, bih1, bhh1,
        wih2, whh2, bih2, bhh2, fcw, fcb, out, flags, ring0, ring1);
}